// Round 1
// baseline (851.797 us; speedup 1.0000x reference)
//
#include <hip/hip_runtime.h>

#define B_   2
#define S_   1024
#define D_   4096
#define HQ_  32
#define HKV_ 8
#define HD_  128
#define SCALE_ 0.08838834764831845f

typedef __attribute__((ext_vector_type(8))) short s16x8;
typedef __attribute__((ext_vector_type(4))) short s16x4;
typedef __attribute__((ext_vector_type(4))) float f32x4;

#define MFMA(a,b,c) __builtin_amdgcn_mfma_f32_16x16x32_bf16((a),(b),(c),0,0,0)

__device__ __forceinline__ unsigned short bf16_rne(float x) {
  unsigned u = __float_as_uint(x);
  u += 0x7fffu + ((u >> 16) & 1u);
  return (unsigned short)(u >> 16);
}
__device__ __forceinline__ float bf16_up(unsigned short h) {
  return __uint_as_float(((unsigned)h) << 16);
}
__device__ __forceinline__ void split2(float x, unsigned short& h, unsigned short& l) {
  h = bf16_rne(x);
  l = bf16_rne(x - bf16_up(h));
}

// ---------------------------------------------------------------------------
// GEMM core: C[m0:m0+128, n0:n0+256] = A(2048x4096) @ W(4096 x ldw)
// fp32 in/out, bf16 hi/lo split 3-pass MFMA. 512 threads = 8 waves (2m x 4n),
// each wave computes 64x64 (4x4 frags of 16x16x32).
// ---------------------------------------------------------------------------
__device__ __forceinline__ void gemm_core_128x256(
    const float* __restrict__ A, const float* __restrict__ W,
    float* __restrict__ C, int ldw, int m0, int n0)
{
  __shared__ unsigned short Ah[128][40];
  __shared__ unsigned short Al[128][40];
  __shared__ unsigned short Bh[256][40];
  __shared__ unsigned short Bl[256][40];

  const int tid  = threadIdx.x;
  const int lane = tid & 63;
  const int wid  = tid >> 6;
  const int wm   = (wid >> 2) * 64;   // 0 or 64
  const int wn   = (wid & 3) * 64;    // 0..192
  const int lr   = lane & 15;
  const int lg   = lane >> 4;

  f32x4 acc[4][4];
#pragma unroll
  for (int i = 0; i < 4; ++i)
#pragma unroll
    for (int j = 0; j < 4; ++j) acc[i][j] = (f32x4){0.f, 0.f, 0.f, 0.f};

  const int ar  = tid >> 3;          // 0..63 (A row base)
  const int ak  = (tid & 7) * 4;     // A k offset
  const int bn  = tid & 255;         // B col
  const int bk0 = (tid >> 8) * 16;   // 0 or 16

  for (int kt = 0; kt < D_ / 32; ++kt) {
    const int k0 = kt * 32;
    __syncthreads();
    // ---- stage A (128x32 fp32 -> hi/lo bf16) ----
#pragma unroll
    for (int j = 0; j < 2; ++j) {
      int r = ar + 64 * j;
      float4 v = *reinterpret_cast<const float4*>(&A[(size_t)(m0 + r) * D_ + k0 + ak]);
      unsigned short h0,h1,h2,h3,l0,l1,l2,l3;
      split2(v.x,h0,l0); split2(v.y,h1,l1); split2(v.z,h2,l2); split2(v.w,h3,l3);
      *reinterpret_cast<s16x4*>(&Ah[r][ak]) = (s16x4){(short)h0,(short)h1,(short)h2,(short)h3};
      *reinterpret_cast<s16x4*>(&Al[r][ak]) = (s16x4){(short)l0,(short)l1,(short)l2,(short)l3};
    }
    // ---- stage B (32x256 fp32 -> transposed hi/lo bf16) ----
    {
      const float* wp = W + (size_t)(k0 + bk0) * ldw + (n0 + bn);
#pragma unroll
      for (int q = 0; q < 4; ++q) {
        float v0 = wp[(q*4 + 0) * (size_t)ldw];
        float v1 = wp[(q*4 + 1) * (size_t)ldw];
        float v2 = wp[(q*4 + 2) * (size_t)ldw];
        float v3 = wp[(q*4 + 3) * (size_t)ldw];
        unsigned short h0,h1,h2,h3,l0,l1,l2,l3;
        split2(v0,h0,l0); split2(v1,h1,l1); split2(v2,h2,l2); split2(v3,h3,l3);
        *reinterpret_cast<s16x4*>(&Bh[bn][bk0 + q*4]) = (s16x4){(short)h0,(short)h1,(short)h2,(short)h3};
        *reinterpret_cast<s16x4*>(&Bl[bn][bk0 + q*4]) = (s16x4){(short)l0,(short)l1,(short)l2,(short)l3};
      }
    }
    __syncthreads();
    // ---- fragments + MFMA ----
    s16x8 a_h[4], a_l[4], b_h[4], b_l[4];
#pragma unroll
    for (int mf = 0; mf < 4; ++mf) {
      a_h[mf] = *reinterpret_cast<const s16x8*>(&Ah[wm + mf*16 + lr][lg*8]);
      a_l[mf] = *reinterpret_cast<const s16x8*>(&Al[wm + mf*16 + lr][lg*8]);
    }
#pragma unroll
    for (int nf = 0; nf < 4; ++nf) {
      b_h[nf] = *reinterpret_cast<const s16x8*>(&Bh[wn + nf*16 + lr][lg*8]);
      b_l[nf] = *reinterpret_cast<const s16x8*>(&Bl[wn + nf*16 + lr][lg*8]);
    }
#pragma unroll
    for (int mf = 0; mf < 4; ++mf)
#pragma unroll
      for (int nf = 0; nf < 4; ++nf) {
        acc[mf][nf] = MFMA(a_h[mf], b_h[nf], acc[mf][nf]);
        acc[mf][nf] = MFMA(a_l[mf], b_h[nf], acc[mf][nf]);
        acc[mf][nf] = MFMA(a_h[mf], b_l[nf], acc[mf][nf]);
      }
  }
  // ---- epilogue ----
#pragma unroll
  for (int mf = 0; mf < 4; ++mf)
#pragma unroll
    for (int nf = 0; nf < 4; ++nf)
#pragma unroll
      for (int r = 0; r < 4; ++r) {
        int row = m0 + wm + mf*16 + lg*4 + r;
        int col = n0 + wn + nf*16 + lr;
        C[(size_t)row * ldw + col] = acc[mf][nf][r];
      }
}

__global__ __launch_bounds__(512) void gemm_qkv_kernel(
    const float* __restrict__ X,
    const float* __restrict__ Wq, const float* __restrict__ Wk,
    const float* __restrict__ Wv,
    float* __restrict__ qb, float* __restrict__ kb, float* __restrict__ vb)
{
  int nb = blockIdx.x;            // 0..23
  int m0 = blockIdx.y * 128;
  const float* W; float* C; int ldw, n0;
  if (nb < 16)      { W = Wq; C = qb; ldw = HQ_*HD_;  n0 = nb * 256; }
  else if (nb < 20) { W = Wk; C = kb; ldw = HKV_*HD_; n0 = (nb-16) * 256; }
  else              { W = Wv; C = vb; ldw = HKV_*HD_; n0 = (nb-20) * 256; }
  gemm_core_128x256(X, W, C, ldw, m0, n0);
}

__global__ __launch_bounds__(512) void gemm_out_kernel(
    const float* __restrict__ A, const float* __restrict__ Wo, float* __restrict__ out)
{
  gemm_core_128x256(A, Wo, out, D_, blockIdx.y * 128, blockIdx.x * 256);
}

// ---------------------------------------------------------------------------
// RoPE in-place on q (b,s,32,128) and k (b,s,8,128), fp32.
// ---------------------------------------------------------------------------
__global__ __launch_bounds__(256) void rope_kernel(
    float* __restrict__ qb, float* __restrict__ kb,
    const float* __restrict__ cosT, const float* __restrict__ sinT)
{
  int idx = blockIdx.x * 256 + threadIdx.x;
  const int nq = B_ * S_ * HQ_ * (HD_/2);
  const int nk = B_ * S_ * HKV_ * (HD_/2);
  if (idx < nq) {
    int j = idx & 63;
    int h = (idx >> 6) & (HQ_ - 1);
    int bs = idx >> 11;
    float* p = qb + ((size_t)bs * HQ_ + h) * HD_;
    const float* cp = cosT + (size_t)bs * HD_;
    const float* sp = sinT + (size_t)bs * HD_;
    float x1 = p[j], x2 = p[j + 64];
    p[j]      = x1 * cp[j]      - x2 * sp[j];
    p[j + 64] = x2 * cp[j + 64] + x1 * sp[j + 64];
  } else if (idx < nq + nk) {
    int t2 = idx - nq;
    int j = t2 & 63;
    int h = (t2 >> 6) & (HKV_ - 1);
    int bs = t2 >> 9;
    float* p = kb + ((size_t)bs * HKV_ + h) * HD_;
    const float* cp = cosT + (size_t)bs * HD_;
    const float* sp = sinT + (size_t)bs * HD_;
    float x1 = p[j], x2 = p[j + 64];
    p[j]      = x1 * cp[j]      - x2 * sp[j];
    p[j + 64] = x2 * cp[j + 64] + x1 * sp[j + 64];
  }
}

// ---------------------------------------------------------------------------
// Flash attention: grid (8 qtiles, 64 b*h), 512 thr = 8 waves.
// Each wave: 16 q rows. KV tile = 64. Online softmax; 3-pass hi/lo MFMA.
// ---------------------------------------------------------------------------
__global__ __launch_bounds__(512) void attn_kernel(
    const float* __restrict__ qb, const float* __restrict__ kb,
    const float* __restrict__ vb, float* __restrict__ ob)
{
  __shared__ unsigned short Kh[64][136], Kl[64][136];   // K tile, row-major in d
  __shared__ unsigned short Vh[128][72], Vl[128][72];   // V tile transposed [d][kk]
  __shared__ unsigned short Ph[8][16][72], Pl[8][16][72]; // per-wave P

  const int tid  = threadIdx.x;
  const int lane = tid & 63;
  const int wid  = tid >> 6;
  const int lr   = lane & 15;
  const int lg   = lane >> 4;
  const int qt   = blockIdx.x;          // 0..7
  const int bh   = blockIdx.y;          // 0..63
  const int b    = bh >> 5, h = bh & 31, kvh = h >> 2;

  // ---- load this wave's Q rows into A-fragments (hi/lo) ----
  s16x8 qh[4], ql[4];
  {
    const int qrow = qt * 128 + wid * 16 + lr;
    const float* qp = qb + ((size_t)((b * S_ + qrow) * HQ_ + h)) * HD_;
#pragma unroll
    for (int kc = 0; kc < 4; ++kc) {
      const float* qp2 = qp + kc * 32 + lg * 8;
      float4 v0 = *reinterpret_cast<const float4*>(qp2);
      float4 v1 = *reinterpret_cast<const float4*>(qp2 + 4);
      unsigned short hh[8], ll[8];
      split2(v0.x,hh[0],ll[0]); split2(v0.y,hh[1],ll[1]);
      split2(v0.z,hh[2],ll[2]); split2(v0.w,hh[3],ll[3]);
      split2(v1.x,hh[4],ll[4]); split2(v1.y,hh[5],ll[5]);
      split2(v1.z,hh[6],ll[6]); split2(v1.w,hh[7],ll[7]);
      qh[kc] = (s16x8){(short)hh[0],(short)hh[1],(short)hh[2],(short)hh[3],
                       (short)hh[4],(short)hh[5],(short)hh[6],(short)hh[7]};
      ql[kc] = (s16x8){(short)ll[0],(short)ll[1],(short)ll[2],(short)ll[3],
                       (short)ll[4],(short)ll[5],(short)ll[6],(short)ll[7]};
    }
  }

  f32x4 acc_o[8];
#pragma unroll
  for (int df = 0; df < 8; ++df) acc_o[df] = (f32x4){0.f, 0.f, 0.f, 0.f};
  float m_run[4] = {-1e30f, -1e30f, -1e30f, -1e30f};
  float l_run[4] = {0.f, 0.f, 0.f, 0.f};

  const float* kbase = kb + ((size_t)(b * S_) * HKV_ + kvh) * HD_;
  const float* vbase = vb + ((size_t)(b * S_) * HKV_ + kvh) * HD_;

  for (int t = 0; t < S_ / 64; ++t) {
    const int kk0 = t * 64;
    __syncthreads();
    // ---- stage K tile (64 x 128) ----
#pragma unroll
    for (int j = 0; j < 4; ++j) {
      int idx = tid + 512 * j;
      int kk = idx >> 5, dq = (idx & 31) * 4;
      float4 v = *reinterpret_cast<const float4*>(kbase + (size_t)(kk0 + kk) * (HKV_*HD_) + dq);
      unsigned short h0,h1,h2,h3,l0,l1,l2,l3;
      split2(v.x,h0,l0); split2(v.y,h1,l1); split2(v.z,h2,l2); split2(v.w,h3,l3);
      *reinterpret_cast<s16x4*>(&Kh[kk][dq]) = (s16x4){(short)h0,(short)h1,(short)h2,(short)h3};
      *reinterpret_cast<s16x4*>(&Kl[kk][dq]) = (s16x4){(short)l0,(short)l1,(short)l2,(short)l3};
    }
    // ---- stage V tile transposed (64 x 128 -> [d][kk]) ----
    {
      int d = tid & 127;
      int kkb = (tid >> 7) * 16;
      const float* vcol = vbase + d;
#pragma unroll
      for (int jq = 0; jq < 4; ++jq) {
        unsigned short h4[4], l4[4];
#pragma unroll
        for (int e = 0; e < 4; ++e) {
          float val = vcol[(size_t)(kk0 + kkb + jq*4 + e) * (HKV_*HD_)];
          split2(val, h4[e], l4[e]);
        }
        *reinterpret_cast<s16x4*>(&Vh[d][kkb + jq*4]) = (s16x4){(short)h4[0],(short)h4[1],(short)h4[2],(short)h4[3]};
        *reinterpret_cast<s16x4*>(&Vl[d][kkb + jq*4]) = (s16x4){(short)l4[0],(short)l4[1],(short)l4[2],(short)l4[3]};
      }
    }
    __syncthreads();
    // ---- QK^T (16 x 64 per wave) ----
    f32x4 accs[4];
#pragma unroll
    for (int nf = 0; nf < 4; ++nf) accs[nf] = (f32x4){0.f, 0.f, 0.f, 0.f};
#pragma unroll
    for (int nf = 0; nf < 4; ++nf) {
      int krow = nf * 16 + lr;
#pragma unroll
      for (int kc = 0; kc < 4; ++kc) {
        s16x8 kh8 = *reinterpret_cast<const s16x8*>(&Kh[krow][kc*32 + lg*8]);
        s16x8 kl8 = *reinterpret_cast<const s16x8*>(&Kl[krow][kc*32 + lg*8]);
        accs[nf] = MFMA(qh[kc], kh8, accs[nf]);
        accs[nf] = MFMA(ql[kc], kh8, accs[nf]);
        accs[nf] = MFMA(qh[kc], kl8, accs[nf]);
      }
    }
#pragma unroll
    for (int nf = 0; nf < 4; ++nf) accs[nf] *= SCALE_;
    // ---- online softmax ----
    float corr[4], rsum[4];
#pragma unroll
    for (int r = 0; r < 4; ++r) {
      float t0 = fmaxf(fmaxf(accs[0][r], accs[1][r]), fmaxf(accs[2][r], accs[3][r]));
      t0 = fmaxf(t0, __shfl_xor(t0, 1));
      t0 = fmaxf(t0, __shfl_xor(t0, 2));
      t0 = fmaxf(t0, __shfl_xor(t0, 4));
      t0 = fmaxf(t0, __shfl_xor(t0, 8));
      float mnew = fmaxf(m_run[r], t0);
      corr[r] = __expf(m_run[r] - mnew);
      m_run[r] = mnew;
      rsum[r] = 0.f;
    }
#pragma unroll
    for (int nf = 0; nf < 4; ++nf)
#pragma unroll
      for (int r = 0; r < 4; ++r) {
        float p = __expf(accs[nf][r] - m_run[r]);
        rsum[r] += p;
        unsigned short ph, pl;
        split2(p, ph, pl);
        Ph[wid][lg*4 + r][nf*16 + lr] = ph;
        Pl[wid][lg*4 + r][nf*16 + lr] = pl;
      }
#pragma unroll
    for (int r = 0; r < 4; ++r) {
      float s = rsum[r];
      s += __shfl_xor(s, 1); s += __shfl_xor(s, 2);
      s += __shfl_xor(s, 4); s += __shfl_xor(s, 8);
      l_run[r] = l_run[r] * corr[r] + s;
    }
#pragma unroll
    for (int df = 0; df < 8; ++df)
#pragma unroll
      for (int r = 0; r < 4; ++r) acc_o[df][r] *= corr[r];
    // ---- PV (wave-local P; compiler inserts lgkmcnt waits) ----
    s16x8 pa_h[2], pa_l[2];
#pragma unroll
    for (int kc = 0; kc < 2; ++kc) {
      pa_h[kc] = *reinterpret_cast<const s16x8*>(&Ph[wid][lr][kc*32 + lg*8]);
      pa_l[kc] = *reinterpret_cast<const s16x8*>(&Pl[wid][lr][kc*32 + lg*8]);
    }
#pragma unroll
    for (int df = 0; df < 8; ++df) {
      int dcol = df * 16 + lr;
#pragma unroll
      for (int kc = 0; kc < 2; ++kc) {
        s16x8 vh8 = *reinterpret_cast<const s16x8*>(&Vh[dcol][kc*32 + lg*8]);
        s16x8 vl8 = *reinterpret_cast<const s16x8*>(&Vl[dcol][kc*32 + lg*8]);
        acc_o[df] = MFMA(pa_h[kc], vh8, acc_o[df]);
        acc_o[df] = MFMA(pa_l[kc], vh8, acc_o[df]);
        acc_o[df] = MFMA(pa_h[kc], vl8, acc_o[df]);
      }
    }
  }
  // ---- write O = acc / l ----
  float inv_l[4];
#pragma unroll
  for (int r = 0; r < 4; ++r) inv_l[r] = 1.f / l_run[r];
#pragma unroll
  for (int df = 0; df < 8; ++df)
#pragma unroll
    for (int r = 0; r < 4; ++r) {
      int row = qt * 128 + wid * 16 + lg * 4 + r;
      ob[((size_t)((b * S_ + row) * HQ_ + h)) * HD_ + df*16 + lr] = acc_o[df][r] * inv_l[r];
    }
}

// ---------------------------------------------------------------------------
extern "C" void kernel_launch(void* const* d_in, const int* in_sizes, int n_in,
                              void* d_out, int out_size, void* d_ws, size_t ws_size,
                              hipStream_t stream)
{
  const float* hs   = (const float*)d_in[0];
  const float* cosT = (const float*)d_in[1];
  const float* sinT = (const float*)d_in[2];
  const float* Wq   = (const float*)d_in[3];
  const float* Wk   = (const float*)d_in[4];
  const float* Wv   = (const float*)d_in[5];
  const float* Wo   = (const float*)d_in[6];
  float* out = (float*)d_out;

  float* qb = (float*)d_ws;                       // 2048*4096 fp32
  float* kb = qb + (size_t)B_*S_*HQ_*HD_;         // 2048*1024
  float* vb = kb + (size_t)B_*S_*HKV_*HD_;        // 2048*1024
  float* ab = vb + (size_t)B_*S_*HKV_*HD_;        // 2048*4096

  // 1) fused QKV projection
  gemm_qkv_kernel<<<dim3(24, 16), 512, 0, stream>>>(hs, Wq, Wk, Wv, qb, kb, vb);
  // 2) RoPE on q, k (in place)
  int total = B_*S_*HQ_*(HD_/2) + B_*S_*HKV_*(HD_/2);
  rope_kernel<<<dim3((total + 255)/256), 256, 0, stream>>>(qb, kb, cosT, sinT);
  // 3) flash attention
  attn_kernel<<<dim3(8, 64), 512, 0, stream>>>(qb, kb, vb, ab);
  // 4) output projection
  gemm_out_kernel<<<dim3(16, 16), 512, 0, stream>>>(ab, Wo, out);
}